// Round 3
// baseline (400.644 us; speedup 1.0000x reference)
//
#include <hip/hip_runtime.h>
#include <math.h>

#define N_NODES 50000
#define E_ORIG  500000
#define E_TOT   550000
#define NB      196    // scan blocks: 196*256 = 50176 >= N_NODES
#define AGG_G   1568   // agg blocks per slice; total grid = 8*AGG_G

typedef _Float16 half8 __attribute__((ext_vector_type(8)));
typedef _Float16 half4 __attribute__((ext_vector_type(4)));
typedef float    v4f   __attribute__((ext_vector_type(4)));

// ------------------------------------------------------------------
// Fused prep: W1/W2 transpose+cast, vs2/vd2 = W2 @ a2, edge degree
// count (deg pre-zeroed by hipMemsetAsync).
// ------------------------------------------------------------------
__global__ void k_prepw(const float* __restrict__ W1, const float* __restrict__ W2,
                        const float* __restrict__ as2, const float* __restrict__ ad2,
                        const int* __restrict__ ei,
                        _Float16* __restrict__ w1t, _Float16* __restrict__ w2t,
                        float* __restrict__ vs2, float* __restrict__ vd2,
                        int* __restrict__ deg) {
    int i = blockIdx.x * blockDim.x + threadIdx.x;
    if (i < E_TOT) {
        int d = (i < E_ORIG) ? ei[E_ORIG + i] : (i - E_ORIG);
        atomicAdd(&deg[d], 1);
        return;
    }
    int j = i - E_TOT;
    if (j < 128 * 256) {
        int k = j >> 8, c = j & 255;
        w1t[(size_t)c * 128 + k] = (_Float16)W1[j];
        return;
    }
    j -= 128 * 256;
    if (j < 256 * 256) {
        int k = j >> 8, c = j & 255;
        w2t[(size_t)c * 256 + k] = (_Float16)W2[j];
        return;
    }
    j -= 256 * 256;
    if (j < 256) {
        float s = 0.f, d = 0.f;
        for (int c = 0; c < 256; c++) {
            float w = W2[(size_t)j * 256 + c];
            s += w * as2[c];
            d += w * ad2[c];
        }
        vs2[j] = s;
        vd2[j] = d;
    }
}

// ------------------------------------------------------------------
// CSR scan + scatter
// ------------------------------------------------------------------
__global__ __launch_bounds__(256) void k_blocksum(const int* __restrict__ deg,
                                                  int* __restrict__ bsum) {
    int t = threadIdx.x;
    int i = blockIdx.x * 256 + t;
    int v = (i < N_NODES) ? deg[i] : 0;
#pragma unroll
    for (int mk = 1; mk < 64; mk <<= 1) v += __shfl_xor(v, mk, 64);
    __shared__ int ws[4];
    if ((t & 63) == 0) ws[t >> 6] = v;
    __syncthreads();
    if (t == 0) bsum[blockIdx.x] = ws[0] + ws[1] + ws[2] + ws[3];
}

__global__ __launch_bounds__(256) void k_scanbsum(const int* __restrict__ bsum,
                                                  int* __restrict__ boff) {
    __shared__ int s[256];
    int t = threadIdx.x;
    int v = (t < NB) ? bsum[t] : 0;
    s[t] = v;
    __syncthreads();
    for (int o = 1; o < 256; o <<= 1) {
        int x = (t >= o) ? s[t - o] : 0;
        __syncthreads();
        s[t] += x;
        __syncthreads();
    }
    if (t <= NB) boff[t] = (t == 0) ? 0 : s[t - 1];
}

__global__ __launch_bounds__(256) void k_offsets(const int* __restrict__ deg,
                                                 const int* __restrict__ boff,
                                                 int* __restrict__ offsets,
                                                 int* __restrict__ cur) {
    __shared__ int s[256];
    int t = threadIdx.x;
    int i = blockIdx.x * 256 + t;
    int v = (i < N_NODES) ? deg[i] : 0;
    s[t] = v;
    __syncthreads();
    for (int o = 1; o < 256; o <<= 1) {
        int x = (t >= o) ? s[t - o] : 0;
        __syncthreads();
        s[t] += x;
        __syncthreads();
    }
    int off = boff[blockIdx.x] + s[t] - v;  // exclusive
    if (i <= N_NODES) {
        offsets[i] = off;
        if (i < N_NODES) cur[i] = off;
    }
}

__global__ void k_scatter(const int* __restrict__ ei, int* __restrict__ cur,
                          int* __restrict__ csr_src) {
    int e = blockIdx.x * blockDim.x + threadIdx.x;
    if (e >= E_TOT) return;
    int s, d;
    if (e < E_ORIG) { s = ei[e]; d = ei[E_ORIG + e]; }
    else            { s = e - E_ORIG; d = s; }
    int slot = atomicAdd(&cur[d], 1);
    csr_src[slot] = s;
}

// ------------------------------------------------------------------
// GEMM1: H[slice-major 8][N][32] = cvt16(X[N,128]) @ w1t^T.
// es/ed stored HEAD-MAJOR [8][N] for per-XCD slice locality.
// ------------------------------------------------------------------
__global__ __launch_bounds__(256) void k_gemm1(
    const float* __restrict__ X, const _Float16* __restrict__ Bt,
    const float* __restrict__ a_s, const float* __restrict__ a_d,
    _Float16* __restrict__ H, float* __restrict__ es, float* __restrict__ ed) {
    int t = threadIdx.x, w = t >> 6, lane = t & 63;
    int quad = lane >> 4, l16 = lane & 15;
    int row0 = blockIdx.x * 32;
    int colbase = w * 64;

    v4f acc[2][4];
#pragma unroll
    for (int i = 0; i < 2; i++)
#pragma unroll
        for (int j = 0; j < 4; j++) acc[i][j] = (v4f){0.f, 0.f, 0.f, 0.f};

    int r0 = row0 + l16;      if (r0 >= N_NODES) r0 = N_NODES - 1;
    int r1 = row0 + 16 + l16; if (r1 >= N_NODES) r1 = N_NODES - 1;
    const float4* a0p = (const float4*)(X + (size_t)r0 * 128) + quad * 2;
    const float4* a1p = (const float4*)(X + (size_t)r1 * 128) + quad * 2;
    const half8* bp[4];
#pragma unroll
    for (int ct = 0; ct < 4; ct++)
        bp[ct] = (const half8*)(Bt + (size_t)(colbase + ct * 16 + l16) * 128 + quad * 8);

#pragma unroll
    for (int kc = 0; kc < 4; kc++) {
        float4 f0 = a0p[kc * 8], f1 = a0p[kc * 8 + 1];
        float4 f2 = a1p[kc * 8], f3 = a1p[kc * 8 + 1];
        half8 av0 = (half8){(_Float16)f0.x, (_Float16)f0.y, (_Float16)f0.z, (_Float16)f0.w,
                            (_Float16)f1.x, (_Float16)f1.y, (_Float16)f1.z, (_Float16)f1.w};
        half8 av1 = (half8){(_Float16)f2.x, (_Float16)f2.y, (_Float16)f2.z, (_Float16)f2.w,
                            (_Float16)f3.x, (_Float16)f3.y, (_Float16)f3.z, (_Float16)f3.w};
#pragma unroll
        for (int ct = 0; ct < 4; ct++) {
            half8 bv = bp[ct][kc * 4];
            acc[0][ct] = __builtin_amdgcn_mfma_f32_16x16x32_f16(av0, bv, acc[0][ct], 0, 0, 0);
            acc[1][ct] = __builtin_amdgcn_mfma_f32_16x16x32_f16(av1, bv, acc[1][ct], 0, 0, 0);
        }
    }

    float asv[4], adv[4];
#pragma unroll
    for (int ct = 0; ct < 4; ct++) {
        asv[ct] = a_s[colbase + ct * 16 + l16];
        adv[ct] = a_d[colbase + ct * 16 + l16];
    }
#pragma unroll
    for (int rt = 0; rt < 2; rt++) {
#pragma unroll
        for (int hp = 0; hp < 2; hp++) {
#pragma unroll
            for (int reg = 0; reg < 4; reg++) {
                float ps = acc[rt][2 * hp][reg] * asv[2 * hp] +
                           acc[rt][2 * hp + 1][reg] * asv[2 * hp + 1];
                float pd = acc[rt][2 * hp][reg] * adv[2 * hp] +
                           acc[rt][2 * hp + 1][reg] * adv[2 * hp + 1];
#pragma unroll
                for (int mk = 1; mk < 16; mk <<= 1) {
                    ps += __shfl_xor(ps, mk, 64);
                    pd += __shfl_xor(pd, mk, 64);
                }
                if (l16 == 0) {
                    int row = row0 + rt * 16 + quad * 4 + reg;
                    if (row < N_NODES) {
                        int head = w * 2 + hp;
                        es[(size_t)head * N_NODES + row] = ps;   // head-major
                        ed[(size_t)head * N_NODES + row] = pd;
                    }
                }
            }
        }
    }

    // 2-pass LDS-staged f16 store (16 rows per pass) -> slice-major H
    __shared__ _Float16 SH[16][264];
#pragma unroll
    for (int rt = 0; rt < 2; rt++) {
        if (rt) __syncthreads();
#pragma unroll
        for (int ct = 0; ct < 4; ct++)
#pragma unroll
            for (int reg = 0; reg < 4; reg++)
                SH[quad * 4 + reg][colbase + ct * 16 + l16] = (_Float16)acc[rt][ct][reg];
        __syncthreads();
#pragma unroll
        for (int j = 0; j < 2; j++) {
            int c = j * 256 + t;
            int row = c >> 5, col8 = c & 31;
            int gr = row0 + rt * 16 + row;
            if (gr < N_NODES) {
                int head = col8 >> 2, sub = col8 & 3;
                *(half8*)(H + ((size_t)head * N_NODES + gr) * 32 + sub * 8) =
                    *(const half8*)&SH[row][col8 * 8];
            }
        }
    }
}

// ------------------------------------------------------------------
// GEMM2: OUT[N,256] = A[N,256] @ w2t^T + bias, f32 out. (row-major A)
// ------------------------------------------------------------------
__global__ __launch_bounds__(256) void k_gemm2(
    const _Float16* __restrict__ A, const _Float16* __restrict__ Bt,
    const float* __restrict__ bias, float* __restrict__ OUT) {
    int t = threadIdx.x, w = t >> 6, lane = t & 63;
    int quad = lane >> 4, l16 = lane & 15;
    int row0 = blockIdx.x * 32;
    int colbase = w * 64;

    v4f acc[2][4];
#pragma unroll
    for (int i = 0; i < 2; i++)
#pragma unroll
        for (int j = 0; j < 4; j++) acc[i][j] = (v4f){0.f, 0.f, 0.f, 0.f};

    int r0 = row0 + l16;      if (r0 >= N_NODES) r0 = N_NODES - 1;
    int r1 = row0 + 16 + l16; if (r1 >= N_NODES) r1 = N_NODES - 1;
    const half8* a0 = (const half8*)(A + (size_t)r0 * 256 + quad * 8);
    const half8* a1 = (const half8*)(A + (size_t)r1 * 256 + quad * 8);
    const half8* bp[4];
#pragma unroll
    for (int ct = 0; ct < 4; ct++)
        bp[ct] = (const half8*)(Bt + (size_t)(colbase + ct * 16 + l16) * 256 + quad * 8);

#pragma unroll
    for (int kc = 0; kc < 8; kc++) {
        half8 av0 = a0[kc * 4];
        half8 av1 = a1[kc * 4];
#pragma unroll
        for (int ct = 0; ct < 4; ct++) {
            half8 bv = bp[ct][kc * 4];
            acc[0][ct] = __builtin_amdgcn_mfma_f32_16x16x32_f16(av0, bv, acc[0][ct], 0, 0, 0);
            acc[1][ct] = __builtin_amdgcn_mfma_f32_16x16x32_f16(av1, bv, acc[1][ct], 0, 0, 0);
        }
    }

    __shared__ float SF[16][260];
#pragma unroll
    for (int rt = 0; rt < 2; rt++) {
        if (rt) __syncthreads();
#pragma unroll
        for (int ct = 0; ct < 4; ct++)
#pragma unroll
            for (int reg = 0; reg < 4; reg++)
                SF[quad * 4 + reg][colbase + ct * 16 + l16] = acc[rt][ct][reg];
        __syncthreads();
#pragma unroll
        for (int j = 0; j < 4; j++) {
            int c = j * 256 + t;
            int row = c >> 6, c4 = c & 63;
            int gr = row0 + rt * 16 + row;
            if (gr < N_NODES) {
                float4 v = *(const float4*)&SF[row][c4 * 4];
                float4 bb = ((const float4*)bias)[c4];
                float4 o = make_float4(v.x + bb.x, v.y + bb.y, v.z + bb.z, v.w + bb.w);
                *(float4*)(OUT + (size_t)gr * 256 + c4 * 4) = o;
            }
        }
    }
}

// ------------------------------------------------------------------
// Layer-1 aggregation, R9 XCD-sliced: slice h = blockIdx%8 -> one
// XCD owns one 32-ch head slice (3.2 MB, L2-resident). Per wave:
// 2 nodes x 8 edge-slots x 4 lanes (half8 = 16B gather). Weight
// computed per-lane from head-major es/ed. Shfl-reduce over slots.
// es2/ed2 = per-slice partial dots, atomicAdd (zeroed by memset).
// ------------------------------------------------------------------
__global__ __launch_bounds__(256) void k_agg1(
    const _Float16* __restrict__ Hs, const float* __restrict__ esh,
    const float* __restrict__ edh, const int* __restrict__ offsets,
    const int* __restrict__ csr_src, const float* __restrict__ b1,
    const float* __restrict__ vs2, const float* __restrict__ vd2,
    _Float16* __restrict__ out1s, float* __restrict__ es2,
    float* __restrict__ ed2) {
    int t = threadIdx.x, w = t >> 6, lane = t & 63;
    int h = blockIdx.x & 7;          // slice == XCD (round-robin dispatch)
    int gb = blockIdx.x >> 3;
    int half = lane >> 5;            // node within pair
    int slot = (lane >> 2) & 7;      // edge slot (0..7)
    int oct  = lane & 3;             // 8-channel group

    const _Float16* Hb  = Hs  + (size_t)h * N_NODES * 32;
    const float*    esb = esh + (size_t)h * N_NODES;
    const float*    edb = edh + (size_t)h * N_NODES;

    float bj[8], vsj[8], vdj[8];
#pragma unroll
    for (int j = 0; j < 8; j++) {
        int c = h * 32 + oct * 8 + j;
        bj[j] = b1[c]; vsj[j] = vs2[c]; vdj[j] = vd2[c];
    }

    int stride = AGG_G * 4 * 2;      // nodes covered per sweep
    for (int n0 = (gb * 4 + w) * 2; n0 < N_NODES; n0 += stride) {
        int n = n0 + half;           // n0 even, so n < N_NODES always
        int beg = offsets[n];
        int deg = offsets[n + 1] - beg;
        float edn = edb[n];

        float a[8] = {0.f, 0.f, 0.f, 0.f, 0.f, 0.f, 0.f, 0.f};
        float den = 0.f;
        for (int base = 0; base < deg; base += 8) {
            int off = base + slot;
            int idx = beg + (off < deg ? off : deg - 1);
            int s = csr_src[idx];
            float l = esb[s] + edn;
            l = fmaxf(l, 0.2f * l);
            float wt = (off < deg) ? __expf(l) : 0.f;
            half8 hv = *(const half8*)(Hb + (size_t)s * 32 + oct * 8);
#pragma unroll
            for (int j = 0; j < 8; j++) a[j] += wt * (float)hv[j];
            den += wt;
        }
        // reduce over slot axis (stays within each 32-lane half)
#pragma unroll
        for (int mk = 4; mk <= 16; mk <<= 1) {
#pragma unroll
            for (int j = 0; j < 8; j++) a[j] += __shfl_xor(a[j], mk, 64);
            den += __shfl_xor(den, mk, 64);
        }

        float r = 1.f / (den + 1e-16f);
        half8 ov;
        float ps = 0.f, pd = 0.f;
#pragma unroll
        for (int j = 0; j < 8; j++) {
            float v = a[j] * r + bj[j];
            v = v > 0.f ? v : __expf(v) - 1.f;   // ELU
            ov[j] = (_Float16)v;
            ps += v * vsj[j];
            pd += v * vdj[j];
        }
        if (slot == 0)
            *(half8*)(out1s + ((size_t)h * N_NODES + n) * 32 + oct * 8) = ov;

        ps += __shfl_xor(ps, 1, 64); ps += __shfl_xor(ps, 2, 64);
        pd += __shfl_xor(pd, 1, 64); pd += __shfl_xor(pd, 2, 64);
        if ((lane & 31) == 0) {
            atomicAdd(&es2[n], ps);
            atomicAdd(&ed2[n], pd);
        }
    }
}

// ------------------------------------------------------------------
// Layer-2 aggregation, R9 XCD-sliced: same structure, single-head
// weights from es2/ed2 (complete after k_agg1). xagg row-major.
// ------------------------------------------------------------------
__global__ __launch_bounds__(256) void k_agg2(
    const _Float16* __restrict__ O1s, const float* __restrict__ es2,
    const float* __restrict__ ed2, const int* __restrict__ offsets,
    const int* __restrict__ csr_src, _Float16* __restrict__ xagg) {
    int t = threadIdx.x, w = t >> 6, lane = t & 63;
    int h = blockIdx.x & 7;
    int gb = blockIdx.x >> 3;
    int half = lane >> 5;
    int slot = (lane >> 2) & 7;
    int oct  = lane & 3;

    const _Float16* Ob = O1s + (size_t)h * N_NODES * 32;

    int stride = AGG_G * 4 * 2;
    for (int n0 = (gb * 4 + w) * 2; n0 < N_NODES; n0 += stride) {
        int n = n0 + half;
        int beg = offsets[n];
        int deg = offsets[n + 1] - beg;
        float edn = ed2[n];

        float a[8] = {0.f, 0.f, 0.f, 0.f, 0.f, 0.f, 0.f, 0.f};
        float den = 0.f;
        for (int base = 0; base < deg; base += 8) {
            int off = base + slot;
            int idx = beg + (off < deg ? off : deg - 1);
            int s = csr_src[idx];
            float l = es2[s] + edn;
            l = fmaxf(l, 0.2f * l);
            float wt = (off < deg) ? __expf(l) : 0.f;
            half8 hv = *(const half8*)(Ob + (size_t)s * 32 + oct * 8);
#pragma unroll
            for (int j = 0; j < 8; j++) a[j] += wt * (float)hv[j];
            den += wt;
        }
#pragma unroll
        for (int mk = 4; mk <= 16; mk <<= 1) {
#pragma unroll
            for (int j = 0; j < 8; j++) a[j] += __shfl_xor(a[j], mk, 64);
            den += __shfl_xor(den, mk, 64);
        }

        float r = 1.f / (den + 1e-16f);
        half8 ov;
#pragma unroll
        for (int j = 0; j < 8; j++) ov[j] = (_Float16)(a[j] * r);
        if (slot == 0)
            *(half8*)(xagg + (size_t)n * 256 + h * 32 + oct * 8) = ov;
    }
}

// ------------------------------------------------------------------
extern "C" void kernel_launch(void* const* d_in, const int* in_sizes, int n_in,
                              void* d_out, int out_size, void* d_ws, size_t ws_size,
                              hipStream_t stream) {
    const float* x   = (const float*)d_in[0];
    const int*   ei  = (const int*)d_in[1];
    const float* W1  = (const float*)d_in[2];
    const float* as1 = (const float*)d_in[3];
    const float* ad1 = (const float*)d_in[4];
    const float* b1  = (const float*)d_in[5];
    const float* W2  = (const float*)d_in[6];
    const float* as2 = (const float*)d_in[7];
    const float* ad2 = (const float*)d_in[8];
    const float* b2  = (const float*)d_in[9];
    float* out = (float*)d_out;

    char* ws = (char*)d_ws;
    size_t off = 0;
    auto alloc = [&](size_t bytes) {
        void* p = ws + off;
        off = (off + bytes + 255) & ~(size_t)255;
        return p;
    };
    _Float16* h1h     = (_Float16*)alloc((size_t)N_NODES * 256 * 2);  // slice-major [8][N][32]
    _Float16* out1h   = (_Float16*)alloc((size_t)N_NODES * 256 * 2);  // slice-major [8][N][32]
    _Float16* xagg    = (_Float16*)alloc((size_t)N_NODES * 256 * 2);  // row-major [N][256]
    _Float16* w1t     = (_Float16*)alloc((size_t)128 * 256 * 2);
    _Float16* w2t     = (_Float16*)alloc((size_t)256 * 256 * 2);
    float*    es1     = (float*)alloc((size_t)N_NODES * 8 * 4);       // head-major [8][N]
    float*    ed1     = (float*)alloc((size_t)N_NODES * 8 * 4);       // head-major [8][N]
    float*    es2     = (float*)alloc((size_t)N_NODES * 4);
    float*    ed2     = (float*)alloc((size_t)N_NODES * 4);
    float*    vs2     = (float*)alloc(256 * 4);
    float*    vd2     = (float*)alloc(256 * 4);
    int*      deg     = (int*)alloc((size_t)N_NODES * 4);
    int*      offsets = (int*)alloc((size_t)(N_NODES + 1) * 4);
    int*      cur     = (int*)alloc((size_t)N_NODES * 4);
    int*      csr_src = (int*)alloc((size_t)E_TOT * 4);
    int*      bsum    = (int*)alloc((size_t)NB * 4);
    int*      boff    = (int*)alloc((size_t)(NB + 1) * 4);

    const int TB = 256;
    int gridE = (E_TOT + TB - 1) / TB;
    int gridG = (N_NODES + 31) / 32;   // 32-row GEMM tiles
    int gridA = AGG_G * 8;             // XCD-sliced agg grid

    // CSR build (deg zeroed by memset; count fused into prepw)
    hipMemsetAsync(deg, 0, (size_t)N_NODES * 4, stream);
    hipMemsetAsync(es2, 0, (size_t)N_NODES * 4, stream);
    hipMemsetAsync(ed2, 0, (size_t)N_NODES * 4, stream);
    int prepN = E_TOT + 128 * 256 + 256 * 256 + 256;
    k_prepw<<<(prepN + TB - 1) / TB, TB, 0, stream>>>(W1, W2, as2, ad2, ei,
                                                      w1t, w2t, vs2, vd2, deg);
    k_blocksum<<<NB, TB, 0, stream>>>(deg, bsum);
    k_scanbsum<<<1, TB, 0, stream>>>(bsum, boff);
    k_offsets<<<NB, TB, 0, stream>>>(deg, boff, offsets, cur);
    k_scatter<<<gridE, TB, 0, stream>>>(ei, cur, csr_src);

    // layer 1
    k_gemm1<<<gridG, TB, 0, stream>>>(x, w1t, as1, ad1, h1h, es1, ed1);
    k_agg1<<<gridA, TB, 0, stream>>>(h1h, es1, ed1, offsets, csr_src, b1,
                                     vs2, vd2, out1h, es2, ed2);

    // layer 2: aggregate first (linearity), then GEMM straight to d_out
    k_agg2<<<gridA, TB, 0, stream>>>(out1h, es2, ed2, offsets, csr_src, xagg);
    k_gemm2<<<gridG, TB, 0, stream>>>(xagg, w2t, b2, out);
}

// Round 4
// 388.382 us; speedup vs baseline: 1.0316x; 1.0316x over previous
//
#include <hip/hip_runtime.h>
#include <math.h>

#define N_NODES 50000
#define E_ORIG  500000
#define E_TOT   550000
#define NB      196    // scan blocks: 196*256 = 50176 >= N_NODES

typedef _Float16 half8  __attribute__((ext_vector_type(8)));
typedef _Float16 half4  __attribute__((ext_vector_type(4)));
typedef _Float16 half2v __attribute__((ext_vector_type(2)));
typedef float    v4f    __attribute__((ext_vector_type(4)));

// ------------------------------------------------------------------
// Fused prep: W1/W2 transpose+cast, vs2/vd2 = W2 @ a2, edge degree
// count (deg pre-zeroed by hipMemsetAsync).
// ------------------------------------------------------------------
__global__ void k_prepw(const float* __restrict__ W1, const float* __restrict__ W2,
                        const float* __restrict__ as2, const float* __restrict__ ad2,
                        const int* __restrict__ ei,
                        _Float16* __restrict__ w1t, _Float16* __restrict__ w2t,
                        float* __restrict__ vs2, float* __restrict__ vd2,
                        int* __restrict__ deg) {
    int i = blockIdx.x * blockDim.x + threadIdx.x;
    if (i < E_TOT) {
        int d = (i < E_ORIG) ? ei[E_ORIG + i] : (i - E_ORIG);
        atomicAdd(&deg[d], 1);
        return;
    }
    int j = i - E_TOT;
    if (j < 128 * 256) {
        int k = j >> 8, c = j & 255;
        w1t[(size_t)c * 128 + k] = (_Float16)W1[j];
        return;
    }
    j -= 128 * 256;
    if (j < 256 * 256) {
        int k = j >> 8, c = j & 255;
        w2t[(size_t)c * 256 + k] = (_Float16)W2[j];
        return;
    }
    j -= 256 * 256;
    if (j < 256) {
        float s = 0.f, d = 0.f;
        for (int c = 0; c < 256; c++) {
            float w = W2[(size_t)j * 256 + c];
            s += w * as2[c];
            d += w * ad2[c];
        }
        vs2[j] = s;
        vd2[j] = d;
    }
}

// ------------------------------------------------------------------
// CSR scan + scatter
// ------------------------------------------------------------------
__global__ __launch_bounds__(256) void k_blocksum(const int* __restrict__ deg,
                                                  int* __restrict__ bsum) {
    int t = threadIdx.x;
    int i = blockIdx.x * 256 + t;
    int v = (i < N_NODES) ? deg[i] : 0;
#pragma unroll
    for (int mk = 1; mk < 64; mk <<= 1) v += __shfl_xor(v, mk, 64);
    __shared__ int ws[4];
    if ((t & 63) == 0) ws[t >> 6] = v;
    __syncthreads();
    if (t == 0) bsum[blockIdx.x] = ws[0] + ws[1] + ws[2] + ws[3];
}

__global__ __launch_bounds__(256) void k_scanbsum(const int* __restrict__ bsum,
                                                  int* __restrict__ boff) {
    __shared__ int s[256];
    int t = threadIdx.x;
    int v = (t < NB) ? bsum[t] : 0;
    s[t] = v;
    __syncthreads();
    for (int o = 1; o < 256; o <<= 1) {
        int x = (t >= o) ? s[t - o] : 0;
        __syncthreads();
        s[t] += x;
        __syncthreads();
    }
    if (t <= NB) boff[t] = (t == 0) ? 0 : s[t - 1];
}

__global__ __launch_bounds__(256) void k_offsets(const int* __restrict__ deg,
                                                 const int* __restrict__ boff,
                                                 int* __restrict__ offsets,
                                                 int* __restrict__ cur) {
    __shared__ int s[256];
    int t = threadIdx.x;
    int i = blockIdx.x * 256 + t;
    int v = (i < N_NODES) ? deg[i] : 0;
    s[t] = v;
    __syncthreads();
    for (int o = 1; o < 256; o <<= 1) {
        int x = (t >= o) ? s[t - o] : 0;
        __syncthreads();
        s[t] += x;
        __syncthreads();
    }
    int off = boff[blockIdx.x] + s[t] - v;  // exclusive
    if (i <= N_NODES) {
        offsets[i] = off;
        if (i < N_NODES) cur[i] = off;
    }
}

__global__ void k_scatter(const int* __restrict__ ei, int* __restrict__ cur,
                          int* __restrict__ csr_src, int* __restrict__ csr_dst) {
    int e = blockIdx.x * blockDim.x + threadIdx.x;
    if (e >= E_TOT) return;
    int s, d;
    if (e < E_ORIG) { s = ei[e]; d = ei[E_ORIG + e]; }
    else            { s = e - E_ORIG; d = s; }
    int slot = atomicAdd(&cur[d], 1);
    csr_src[slot] = s;
    csr_dst[slot] = d;
}

// ------------------------------------------------------------------
// GEMM1: H[slice-major 8][N][32] = cvt16(X[N,128]) @ w1t^T.
// es/ed NODE-MAJOR [N][8] (32B records for k_wts1 gathers).
// ------------------------------------------------------------------
__global__ __launch_bounds__(256) void k_gemm1(
    const float* __restrict__ X, const _Float16* __restrict__ Bt,
    const float* __restrict__ a_s, const float* __restrict__ a_d,
    _Float16* __restrict__ H, float* __restrict__ es, float* __restrict__ ed) {
    int t = threadIdx.x, w = t >> 6, lane = t & 63;
    int quad = lane >> 4, l16 = lane & 15;
    int row0 = blockIdx.x * 32;
    int colbase = w * 64;

    v4f acc[2][4];
#pragma unroll
    for (int i = 0; i < 2; i++)
#pragma unroll
        for (int j = 0; j < 4; j++) acc[i][j] = (v4f){0.f, 0.f, 0.f, 0.f};

    int r0 = row0 + l16;      if (r0 >= N_NODES) r0 = N_NODES - 1;
    int r1 = row0 + 16 + l16; if (r1 >= N_NODES) r1 = N_NODES - 1;
    const float4* a0p = (const float4*)(X + (size_t)r0 * 128) + quad * 2;
    const float4* a1p = (const float4*)(X + (size_t)r1 * 128) + quad * 2;
    const half8* bp[4];
#pragma unroll
    for (int ct = 0; ct < 4; ct++)
        bp[ct] = (const half8*)(Bt + (size_t)(colbase + ct * 16 + l16) * 128 + quad * 8);

#pragma unroll
    for (int kc = 0; kc < 4; kc++) {
        float4 f0 = a0p[kc * 8], f1 = a0p[kc * 8 + 1];
        float4 f2 = a1p[kc * 8], f3 = a1p[kc * 8 + 1];
        half8 av0 = (half8){(_Float16)f0.x, (_Float16)f0.y, (_Float16)f0.z, (_Float16)f0.w,
                            (_Float16)f1.x, (_Float16)f1.y, (_Float16)f1.z, (_Float16)f1.w};
        half8 av1 = (half8){(_Float16)f2.x, (_Float16)f2.y, (_Float16)f2.z, (_Float16)f2.w,
                            (_Float16)f3.x, (_Float16)f3.y, (_Float16)f3.z, (_Float16)f3.w};
#pragma unroll
        for (int ct = 0; ct < 4; ct++) {
            half8 bv = bp[ct][kc * 4];
            acc[0][ct] = __builtin_amdgcn_mfma_f32_16x16x32_f16(av0, bv, acc[0][ct], 0, 0, 0);
            acc[1][ct] = __builtin_amdgcn_mfma_f32_16x16x32_f16(av1, bv, acc[1][ct], 0, 0, 0);
        }
    }

    float asv[4], adv[4];
#pragma unroll
    for (int ct = 0; ct < 4; ct++) {
        asv[ct] = a_s[colbase + ct * 16 + l16];
        adv[ct] = a_d[colbase + ct * 16 + l16];
    }
#pragma unroll
    for (int rt = 0; rt < 2; rt++) {
#pragma unroll
        for (int hp = 0; hp < 2; hp++) {
#pragma unroll
            for (int reg = 0; reg < 4; reg++) {
                float ps = acc[rt][2 * hp][reg] * asv[2 * hp] +
                           acc[rt][2 * hp + 1][reg] * asv[2 * hp + 1];
                float pd = acc[rt][2 * hp][reg] * adv[2 * hp] +
                           acc[rt][2 * hp + 1][reg] * adv[2 * hp + 1];
#pragma unroll
                for (int mk = 1; mk < 16; mk <<= 1) {
                    ps += __shfl_xor(ps, mk, 64);
                    pd += __shfl_xor(pd, mk, 64);
                }
                if (l16 == 0) {
                    int row = row0 + rt * 16 + quad * 4 + reg;
                    if (row < N_NODES) {
                        int head = w * 2 + hp;
                        es[(size_t)row * 8 + head] = ps;   // node-major
                        ed[(size_t)row * 8 + head] = pd;
                    }
                }
            }
        }
    }

    // 2-pass LDS-staged f16 store (16 rows per pass) -> slice-major H
    __shared__ _Float16 SH[16][264];
#pragma unroll
    for (int rt = 0; rt < 2; rt++) {
        if (rt) __syncthreads();
#pragma unroll
        for (int ct = 0; ct < 4; ct++)
#pragma unroll
            for (int reg = 0; reg < 4; reg++)
                SH[quad * 4 + reg][colbase + ct * 16 + l16] = (_Float16)acc[rt][ct][reg];
        __syncthreads();
#pragma unroll
        for (int j = 0; j < 2; j++) {
            int c = j * 256 + t;
            int row = c >> 5, col8 = c & 31;
            int gr = row0 + rt * 16 + row;
            if (gr < N_NODES) {
                int head = col8 >> 2, sub = col8 & 3;
                *(half8*)(H + ((size_t)head * N_NODES + gr) * 32 + sub * 8) =
                    *(const half8*)&SH[row][col8 * 8];
            }
        }
    }
}

// ------------------------------------------------------------------
// GEMM2: OUT[N,256] = A[N,256] @ w2t^T + bias, f32 out. (row-major A)
// ------------------------------------------------------------------
__global__ __launch_bounds__(256) void k_gemm2(
    const _Float16* __restrict__ A, const _Float16* __restrict__ Bt,
    const float* __restrict__ bias, float* __restrict__ OUT) {
    int t = threadIdx.x, w = t >> 6, lane = t & 63;
    int quad = lane >> 4, l16 = lane & 15;
    int row0 = blockIdx.x * 32;
    int colbase = w * 64;

    v4f acc[2][4];
#pragma unroll
    for (int i = 0; i < 2; i++)
#pragma unroll
        for (int j = 0; j < 4; j++) acc[i][j] = (v4f){0.f, 0.f, 0.f, 0.f};

    int r0 = row0 + l16;      if (r0 >= N_NODES) r0 = N_NODES - 1;
    int r1 = row0 + 16 + l16; if (r1 >= N_NODES) r1 = N_NODES - 1;
    const half8* a0 = (const half8*)(A + (size_t)r0 * 256 + quad * 8);
    const half8* a1 = (const half8*)(A + (size_t)r1 * 256 + quad * 8);
    const half8* bp[4];
#pragma unroll
    for (int ct = 0; ct < 4; ct++)
        bp[ct] = (const half8*)(Bt + (size_t)(colbase + ct * 16 + l16) * 256 + quad * 8);

#pragma unroll
    for (int kc = 0; kc < 8; kc++) {
        half8 av0 = a0[kc * 4];
        half8 av1 = a1[kc * 4];
#pragma unroll
        for (int ct = 0; ct < 4; ct++) {
            half8 bv = bp[ct][kc * 4];
            acc[0][ct] = __builtin_amdgcn_mfma_f32_16x16x32_f16(av0, bv, acc[0][ct], 0, 0, 0);
            acc[1][ct] = __builtin_amdgcn_mfma_f32_16x16x32_f16(av1, bv, acc[1][ct], 0, 0, 0);
        }
    }

    __shared__ float SF[16][260];
#pragma unroll
    for (int rt = 0; rt < 2; rt++) {
        if (rt) __syncthreads();
#pragma unroll
        for (int ct = 0; ct < 4; ct++)
#pragma unroll
            for (int reg = 0; reg < 4; reg++)
                SF[quad * 4 + reg][colbase + ct * 16 + l16] = acc[rt][ct][reg];
        __syncthreads();
#pragma unroll
        for (int j = 0; j < 4; j++) {
            int c = j * 256 + t;
            int row = c >> 6, c4 = c & 63;
            int gr = row0 + rt * 16 + row;
            if (gr < N_NODES) {
                float4 v = *(const float4*)&SF[row][c4 * 4];
                float4 bb = ((const float4*)bias)[c4];
                float4 o = make_float4(v.x + bb.x, v.y + bb.y, v.z + bb.z, v.w + bb.w);
                *(float4*)(OUT + (size_t)gr * 256 + c4 * 4) = o;
            }
        }
    }
}

// ------------------------------------------------------------------
// Edge-weight precompute, layer 1: per CSR slot, all 8 heads.
// es/ed node-major [N][8] -> two float4 gathers each. Output
// head-major w[8][E] f32 (coalesced store streams).
// ------------------------------------------------------------------
__global__ __launch_bounds__(256) void k_wts1(
    const float* __restrict__ es, const float* __restrict__ ed,
    const int* __restrict__ csr_src, const int* __restrict__ csr_dst,
    float* __restrict__ wout) {
    int e = blockIdx.x * 256 + threadIdx.x;
    if (e >= E_TOT) return;
    int s = csr_src[e], d = csr_dst[e];
    const float4* ep = (const float4*)(es + (size_t)s * 8);
    const float4* dp = (const float4*)(ed + (size_t)d * 8);
    float4 e0 = ep[0], e1 = ep[1], f0 = dp[0], f1 = dp[1];
    float l[8] = {e0.x + f0.x, e0.y + f0.y, e0.z + f0.z, e0.w + f0.w,
                  e1.x + f1.x, e1.y + f1.y, e1.z + f1.z, e1.w + f1.w};
#pragma unroll
    for (int h = 0; h < 8; h++) {
        float v = l[h];
        v = fmaxf(v, 0.2f * v);
        wout[(size_t)h * E_TOT + e] = __expf(v);
    }
}

// ------------------------------------------------------------------
// Edge-weight precompute, layer 2 (single head).
// ------------------------------------------------------------------
__global__ __launch_bounds__(256) void k_wts2(
    const float* __restrict__ es2, const float* __restrict__ ed2,
    const int* __restrict__ csr_src, const int* __restrict__ csr_dst,
    float* __restrict__ wout) {
    int e = blockIdx.x * 256 + threadIdx.x;
    if (e >= E_TOT) return;
    float l = es2[csr_src[e]] + ed2[csr_dst[e]];
    l = fmaxf(l, 0.2f * l);
    wout[e] = __expf(l);
}

// ------------------------------------------------------------------
// Layer-1 aggregation, R10: XCD-sliced (h = blockIdx%8, 3.2 MB
// L2-resident H slice) + 4 nodes/wave x 16 lanes/node (lane = 2 ch).
// Serial edge loop, precomputed weights -> inner body is just
// {s load, w load, half2 gather, 2 fma, den add}. No cross-lane
// reduce for the aggregate; only es2/ed2 dot reduces over 16 lanes.
// ------------------------------------------------------------------
__global__ __launch_bounds__(256) void k_agg1(
    const _Float16* __restrict__ Hs, const float* __restrict__ w1w,
    const int* __restrict__ offsets, const int* __restrict__ csr_src,
    const float* __restrict__ b1, const float* __restrict__ vs2,
    const float* __restrict__ vd2, _Float16* __restrict__ out1s,
    float* __restrict__ es2, float* __restrict__ ed2) {
    int t = threadIdx.x, w = t >> 6, lane = t & 63;
    int h  = blockIdx.x & 7;        // slice == XCD (round-robin dispatch)
    int gb = blockIdx.x >> 3;
    int g  = lane >> 4;             // node group 0..3
    int c2 = lane & 15;             // channel pair within 32-ch slice
    int n  = gb * 16 + w * 4 + g;   // 3125*16 = 50000 exactly
    int beg = offsets[n];
    int deg = offsets[n + 1] - beg;

    const _Float16* __restrict__ Hb = Hs + (size_t)h * N_NODES * 32 + c2 * 2;
    const float* __restrict__ wb = w1w + (size_t)h * E_TOT + beg;
    const int* __restrict__ sb = csr_src + beg;

    float a0 = 0.f, a1 = 0.f, den = 0.f;
    int i = 0;
    for (; i + 3 < deg; i += 4) {
        int s0 = sb[i], s1 = sb[i + 1], s2 = sb[i + 2], s3 = sb[i + 3];
        float w0 = wb[i], w1 = wb[i + 1], w2 = wb[i + 2], w3 = wb[i + 3];
        half2v h0 = *(const half2v*)(Hb + (size_t)s0 * 32);
        half2v h1 = *(const half2v*)(Hb + (size_t)s1 * 32);
        half2v h2 = *(const half2v*)(Hb + (size_t)s2 * 32);
        half2v h3 = *(const half2v*)(Hb + (size_t)s3 * 32);
        a0 += w0 * (float)h0[0]; a1 += w0 * (float)h0[1];
        a0 += w1 * (float)h1[0]; a1 += w1 * (float)h1[1];
        a0 += w2 * (float)h2[0]; a1 += w2 * (float)h2[1];
        a0 += w3 * (float)h3[0]; a1 += w3 * (float)h3[1];
        den += w0 + w1 + w2 + w3;
    }
    for (; i < deg; i++) {
        int s0 = sb[i];
        float w0 = wb[i];
        half2v h0 = *(const half2v*)(Hb + (size_t)s0 * 32);
        a0 += w0 * (float)h0[0]; a1 += w0 * (float)h0[1];
        den += w0;
    }

    float r = 1.f / (den + 1e-16f);
    int c = h * 32 + c2 * 2;
    float o0 = a0 * r + b1[c];
    float o1 = a1 * r + b1[c + 1];
    o0 = o0 > 0.f ? o0 : __expf(o0) - 1.f;   // ELU
    o1 = o1 > 0.f ? o1 : __expf(o1) - 1.f;
    *(half2v*)(out1s + ((size_t)h * N_NODES + n) * 32 + c2 * 2) =
        (half2v){(_Float16)o0, (_Float16)o1};

    // fused layer-2 attention coefficient partials (this slice's 32 ch)
    float ps = o0 * vs2[c] + o1 * vs2[c + 1];
    float pd = o0 * vd2[c] + o1 * vd2[c + 1];
#pragma unroll
    for (int mk = 1; mk < 16; mk <<= 1) {
        ps += __shfl_xor(ps, mk, 64);
        pd += __shfl_xor(pd, mk, 64);
    }
    if (c2 == 0) {
        atomicAdd(&es2[n], ps);
        atomicAdd(&ed2[n], pd);
    }
}

// ------------------------------------------------------------------
// Layer-2 aggregation, R10: same structure; single-head weights
// precomputed (w2w). Writes xagg row-major for GEMM2.
// ------------------------------------------------------------------
__global__ __launch_bounds__(256) void k_agg2(
    const _Float16* __restrict__ O1s, const float* __restrict__ w2w,
    const int* __restrict__ offsets, const int* __restrict__ csr_src,
    _Float16* __restrict__ xagg) {
    int t = threadIdx.x, w = t >> 6, lane = t & 63;
    int h  = blockIdx.x & 7;
    int gb = blockIdx.x >> 3;
    int g  = lane >> 4;
    int c2 = lane & 15;
    int n  = gb * 16 + w * 4 + g;
    int beg = offsets[n];
    int deg = offsets[n + 1] - beg;

    const _Float16* __restrict__ Ob = O1s + (size_t)h * N_NODES * 32 + c2 * 2;
    const float* __restrict__ wb = w2w + beg;
    const int* __restrict__ sb = csr_src + beg;

    float a0 = 0.f, a1 = 0.f, den = 0.f;
    int i = 0;
    for (; i + 3 < deg; i += 4) {
        int s0 = sb[i], s1 = sb[i + 1], s2 = sb[i + 2], s3 = sb[i + 3];
        float w0 = wb[i], w1 = wb[i + 1], w2 = wb[i + 2], w3 = wb[i + 3];
        half2v h0 = *(const half2v*)(Ob + (size_t)s0 * 32);
        half2v h1 = *(const half2v*)(Ob + (size_t)s1 * 32);
        half2v h2 = *(const half2v*)(Ob + (size_t)s2 * 32);
        half2v h3 = *(const half2v*)(Ob + (size_t)s3 * 32);
        a0 += w0 * (float)h0[0]; a1 += w0 * (float)h0[1];
        a0 += w1 * (float)h1[0]; a1 += w1 * (float)h1[1];
        a0 += w2 * (float)h2[0]; a1 += w2 * (float)h2[1];
        a0 += w3 * (float)h3[0]; a1 += w3 * (float)h3[1];
        den += w0 + w1 + w2 + w3;
    }
    for (; i < deg; i++) {
        int s0 = sb[i];
        float w0 = wb[i];
        half2v h0 = *(const half2v*)(Ob + (size_t)s0 * 32);
        a0 += w0 * (float)h0[0]; a1 += w0 * (float)h0[1];
        den += w0;
    }

    float r = 1.f / (den + 1e-16f);
    *(half2v*)(xagg + (size_t)n * 256 + h * 32 + c2 * 2) =
        (half2v){(_Float16)(a0 * r), (_Float16)(a1 * r)};
}

// ------------------------------------------------------------------
extern "C" void kernel_launch(void* const* d_in, const int* in_sizes, int n_in,
                              void* d_out, int out_size, void* d_ws, size_t ws_size,
                              hipStream_t stream) {
    const float* x   = (const float*)d_in[0];
    const int*   ei  = (const int*)d_in[1];
    const float* W1  = (const float*)d_in[2];
    const float* as1 = (const float*)d_in[3];
    const float* ad1 = (const float*)d_in[4];
    const float* b1  = (const float*)d_in[5];
    const float* W2  = (const float*)d_in[6];
    const float* as2 = (const float*)d_in[7];
    const float* ad2 = (const float*)d_in[8];
    const float* b2  = (const float*)d_in[9];
    float* out = (float*)d_out;

    char* ws = (char*)d_ws;
    size_t off = 0;
    auto alloc = [&](size_t bytes) {
        void* p = ws + off;
        off = (off + bytes + 255) & ~(size_t)255;
        return p;
    };
    _Float16* h1h     = (_Float16*)alloc((size_t)N_NODES * 256 * 2);  // slice-major [8][N][32]
    _Float16* out1h   = (_Float16*)alloc((size_t)N_NODES * 256 * 2);  // slice-major [8][N][32]
    _Float16* xagg    = (_Float16*)alloc((size_t)N_NODES * 256 * 2);  // row-major [N][256]
    _Float16* w1t     = (_Float16*)alloc((size_t)128 * 256 * 2);
    _Float16* w2t     = (_Float16*)alloc((size_t)256 * 256 * 2);
    float*    es1     = (float*)alloc((size_t)N_NODES * 8 * 4);       // node-major [N][8]
    float*    ed1     = (float*)alloc((size_t)N_NODES * 8 * 4);       // node-major [N][8]
    float*    es2     = (float*)alloc((size_t)N_NODES * 4);
    float*    ed2     = (float*)alloc((size_t)N_NODES * 4);
    float*    vs2     = (float*)alloc(256 * 4);
    float*    vd2     = (float*)alloc(256 * 4);
    float*    w1w     = (float*)alloc((size_t)8 * E_TOT * 4);         // head-major [8][E]
    float*    w2w     = (float*)alloc((size_t)E_TOT * 4);
    int*      deg     = (int*)alloc((size_t)N_NODES * 4);
    int*      offsets = (int*)alloc((size_t)(N_NODES + 1) * 4);
    int*      cur     = (int*)alloc((size_t)N_NODES * 4);
    int*      csr_src = (int*)alloc((size_t)E_TOT * 4);
    int*      csr_dst = (int*)alloc((size_t)E_TOT * 4);
    int*      bsum    = (int*)alloc((size_t)NB * 4);
    int*      boff    = (int*)alloc((size_t)(NB + 1) * 4);

    const int TB = 256;
    int gridE = (E_TOT + TB - 1) / TB;
    int gridG = (N_NODES + 31) / 32;   // 32-row GEMM tiles
    int gridA = 3125 * 8;              // 16 nodes/block x 3125 x 8 slices

    // CSR build (deg zeroed by memset; count fused into prepw)
    hipMemsetAsync(deg, 0, (size_t)N_NODES * 4, stream);
    hipMemsetAsync(es2, 0, (size_t)N_NODES * 4, stream);
    hipMemsetAsync(ed2, 0, (size_t)N_NODES * 4, stream);
    int prepN = E_TOT + 128 * 256 + 256 * 256 + 256;
    k_prepw<<<(prepN + TB - 1) / TB, TB, 0, stream>>>(W1, W2, as2, ad2, ei,
                                                      w1t, w2t, vs2, vd2, deg);
    k_blocksum<<<NB, TB, 0, stream>>>(deg, bsum);
    k_scanbsum<<<1, TB, 0, stream>>>(bsum, boff);
    k_offsets<<<NB, TB, 0, stream>>>(deg, boff, offsets, cur);
    k_scatter<<<gridE, TB, 0, stream>>>(ei, cur, csr_src, csr_dst);

    // layer 1
    k_gemm1<<<gridG, TB, 0, stream>>>(x, w1t, as1, ad1, h1h, es1, ed1);
    k_wts1<<<gridE, TB, 0, stream>>>(es1, ed1, csr_src, csr_dst, w1w);
    k_agg1<<<gridA, TB, 0, stream>>>(h1h, w1w, offsets, csr_src, b1,
                                     vs2, vd2, out1h, es2, ed2);

    // layer 2: weights, aggregate (linearity), then GEMM to d_out
    k_wts2<<<gridE, TB, 0, stream>>>(es2, ed2, csr_src, csr_dst, w2w);
    k_agg2<<<gridA, TB, 0, stream>>>(out1h, w2w, offsets, csr_src, xagg);
    k_gemm2<<<gridG, TB, 0, stream>>>(xagg, w2t, b2, out);
}

// Round 5
// 358.240 us; speedup vs baseline: 1.1184x; 1.0841x over previous
//
#include <hip/hip_runtime.h>
#include <math.h>

#define N_NODES 50000
#define E_ORIG  500000
#define E_TOT   550000
#define NB      196    // scan blocks: 196*256 = 50176 >= N_NODES
#define AGG_GB  1563   // ceil(50000/32) node-groups of 32; grid = 8*AGG_GB

typedef _Float16 half8  __attribute__((ext_vector_type(8)));
typedef _Float16 half4  __attribute__((ext_vector_type(4)));
typedef float    v4f    __attribute__((ext_vector_type(4)));
typedef int      int4u  __attribute__((ext_vector_type(4), aligned(4)));

// ------------------------------------------------------------------
// Fused prep: W1/W2 transpose+cast, vs2/vd2 = W2 @ a2, edge degree
// count (deg pre-zeroed by hipMemsetAsync).
// ------------------------------------------------------------------
__global__ void k_prepw(const float* __restrict__ W1, const float* __restrict__ W2,
                        const float* __restrict__ as2, const float* __restrict__ ad2,
                        const int* __restrict__ ei,
                        _Float16* __restrict__ w1t, _Float16* __restrict__ w2t,
                        float* __restrict__ vs2, float* __restrict__ vd2,
                        int* __restrict__ deg) {
    int i = blockIdx.x * blockDim.x + threadIdx.x;
    if (i < E_TOT) {
        int d = (i < E_ORIG) ? ei[E_ORIG + i] : (i - E_ORIG);
        atomicAdd(&deg[d], 1);
        return;
    }
    int j = i - E_TOT;
    if (j < 128 * 256) {
        int k = j >> 8, c = j & 255;
        w1t[(size_t)c * 128 + k] = (_Float16)W1[j];
        return;
    }
    j -= 128 * 256;
    if (j < 256 * 256) {
        int k = j >> 8, c = j & 255;
        w2t[(size_t)c * 256 + k] = (_Float16)W2[j];
        return;
    }
    j -= 256 * 256;
    if (j < 256) {
        float s = 0.f, d = 0.f;
        for (int c = 0; c < 256; c++) {
            float w = W2[(size_t)j * 256 + c];
            s += w * as2[c];
            d += w * ad2[c];
        }
        vs2[j] = s;
        vd2[j] = d;
    }
}

// ------------------------------------------------------------------
// CSR scan + scatter
// ------------------------------------------------------------------
__global__ __launch_bounds__(256) void k_blocksum(const int* __restrict__ deg,
                                                  int* __restrict__ bsum) {
    int t = threadIdx.x;
    int i = blockIdx.x * 256 + t;
    int v = (i < N_NODES) ? deg[i] : 0;
#pragma unroll
    for (int mk = 1; mk < 64; mk <<= 1) v += __shfl_xor(v, mk, 64);
    __shared__ int ws[4];
    if ((t & 63) == 0) ws[t >> 6] = v;
    __syncthreads();
    if (t == 0) bsum[blockIdx.x] = ws[0] + ws[1] + ws[2] + ws[3];
}

__global__ __launch_bounds__(256) void k_scanbsum(const int* __restrict__ bsum,
                                                  int* __restrict__ boff) {
    __shared__ int s[256];
    int t = threadIdx.x;
    int v = (t < NB) ? bsum[t] : 0;
    s[t] = v;
    __syncthreads();
    for (int o = 1; o < 256; o <<= 1) {
        int x = (t >= o) ? s[t - o] : 0;
        __syncthreads();
        s[t] += x;
        __syncthreads();
    }
    if (t <= NB) boff[t] = (t == 0) ? 0 : s[t - 1];
}

__global__ __launch_bounds__(256) void k_offsets(const int* __restrict__ deg,
                                                 const int* __restrict__ boff,
                                                 int* __restrict__ offsets,
                                                 int* __restrict__ cur) {
    __shared__ int s[256];
    int t = threadIdx.x;
    int i = blockIdx.x * 256 + t;
    int v = (i < N_NODES) ? deg[i] : 0;
    s[t] = v;
    __syncthreads();
    for (int o = 1; o < 256; o <<= 1) {
        int x = (t >= o) ? s[t - o] : 0;
        __syncthreads();
        s[t] += x;
        __syncthreads();
    }
    int off = boff[blockIdx.x] + s[t] - v;  // exclusive
    if (i <= N_NODES) {
        offsets[i] = off;
        if (i < N_NODES) cur[i] = off;
    }
}

__global__ void k_scatter(const int* __restrict__ ei, int* __restrict__ cur,
                          int* __restrict__ csr_src) {
    int e = blockIdx.x * blockDim.x + threadIdx.x;
    if (e >= E_TOT) return;
    int s, d;
    if (e < E_ORIG) { s = ei[e]; d = ei[E_ORIG + e]; }
    else            { s = e - E_ORIG; d = s; }
    int slot = atomicAdd(&cur[d], 1);
    csr_src[slot] = s;
}

// ------------------------------------------------------------------
// GEMM1: H[slice-major 8][N][32] = cvt16(X[N,128]) @ w1t^T.
// es/ed HEAD-MAJOR [8][N] (L2-resident 200KB/slice for agg gathers).
// ------------------------------------------------------------------
__global__ __launch_bounds__(256) void k_gemm1(
    const float* __restrict__ X, const _Float16* __restrict__ Bt,
    const float* __restrict__ a_s, const float* __restrict__ a_d,
    _Float16* __restrict__ H, float* __restrict__ es, float* __restrict__ ed) {
    int t = threadIdx.x, w = t >> 6, lane = t & 63;
    int quad = lane >> 4, l16 = lane & 15;
    int row0 = blockIdx.x * 32;
    int colbase = w * 64;

    v4f acc[2][4];
#pragma unroll
    for (int i = 0; i < 2; i++)
#pragma unroll
        for (int j = 0; j < 4; j++) acc[i][j] = (v4f){0.f, 0.f, 0.f, 0.f};

    int r0 = row0 + l16;      if (r0 >= N_NODES) r0 = N_NODES - 1;
    int r1 = row0 + 16 + l16; if (r1 >= N_NODES) r1 = N_NODES - 1;
    const float4* a0p = (const float4*)(X + (size_t)r0 * 128) + quad * 2;
    const float4* a1p = (const float4*)(X + (size_t)r1 * 128) + quad * 2;
    const half8* bp[4];
#pragma unroll
    for (int ct = 0; ct < 4; ct++)
        bp[ct] = (const half8*)(Bt + (size_t)(colbase + ct * 16 + l16) * 128 + quad * 8);

#pragma unroll
    for (int kc = 0; kc < 4; kc++) {
        float4 f0 = a0p[kc * 8], f1 = a0p[kc * 8 + 1];
        float4 f2 = a1p[kc * 8], f3 = a1p[kc * 8 + 1];
        half8 av0 = (half8){(_Float16)f0.x, (_Float16)f0.y, (_Float16)f0.z, (_Float16)f0.w,
                            (_Float16)f1.x, (_Float16)f1.y, (_Float16)f1.z, (_Float16)f1.w};
        half8 av1 = (half8){(_Float16)f2.x, (_Float16)f2.y, (_Float16)f2.z, (_Float16)f2.w,
                            (_Float16)f3.x, (_Float16)f3.y, (_Float16)f3.z, (_Float16)f3.w};
#pragma unroll
        for (int ct = 0; ct < 4; ct++) {
            half8 bv = bp[ct][kc * 4];
            acc[0][ct] = __builtin_amdgcn_mfma_f32_16x16x32_f16(av0, bv, acc[0][ct], 0, 0, 0);
            acc[1][ct] = __builtin_amdgcn_mfma_f32_16x16x32_f16(av1, bv, acc[1][ct], 0, 0, 0);
        }
    }

    float asv[4], adv[4];
#pragma unroll
    for (int ct = 0; ct < 4; ct++) {
        asv[ct] = a_s[colbase + ct * 16 + l16];
        adv[ct] = a_d[colbase + ct * 16 + l16];
    }
#pragma unroll
    for (int rt = 0; rt < 2; rt++) {
#pragma unroll
        for (int hp = 0; hp < 2; hp++) {
#pragma unroll
            for (int reg = 0; reg < 4; reg++) {
                float ps = acc[rt][2 * hp][reg] * asv[2 * hp] +
                           acc[rt][2 * hp + 1][reg] * asv[2 * hp + 1];
                float pd = acc[rt][2 * hp][reg] * adv[2 * hp] +
                           acc[rt][2 * hp + 1][reg] * adv[2 * hp + 1];
#pragma unroll
                for (int mk = 1; mk < 16; mk <<= 1) {
                    ps += __shfl_xor(ps, mk, 64);
                    pd += __shfl_xor(pd, mk, 64);
                }
                if (l16 == 0) {
                    int row = row0 + rt * 16 + quad * 4 + reg;
                    if (row < N_NODES) {
                        int head = w * 2 + hp;
                        es[(size_t)head * N_NODES + row] = ps;   // head-major
                        ed[(size_t)head * N_NODES + row] = pd;
                    }
                }
            }
        }
    }

    // 2-pass LDS-staged f16 store (16 rows per pass) -> slice-major H
    __shared__ _Float16 SH[16][264];
#pragma unroll
    for (int rt = 0; rt < 2; rt++) {
        if (rt) __syncthreads();
#pragma unroll
        for (int ct = 0; ct < 4; ct++)
#pragma unroll
            for (int reg = 0; reg < 4; reg++)
                SH[quad * 4 + reg][colbase + ct * 16 + l16] = (_Float16)acc[rt][ct][reg];
        __syncthreads();
#pragma unroll
        for (int j = 0; j < 2; j++) {
            int c = j * 256 + t;
            int row = c >> 5, col8 = c & 31;
            int gr = row0 + rt * 16 + row;
            if (gr < N_NODES) {
                int head = col8 >> 2, sub = col8 & 3;
                *(half8*)(H + ((size_t)head * N_NODES + gr) * 32 + sub * 8) =
                    *(const half8*)&SH[row][col8 * 8];
            }
        }
    }
}

// ------------------------------------------------------------------
// GEMM2: OUT[N,256] = A[N,256] @ w2t^T + bias, f32 out. (row-major A)
// ------------------------------------------------------------------
__global__ __launch_bounds__(256) void k_gemm2(
    const _Float16* __restrict__ A, const _Float16* __restrict__ Bt,
    const float* __restrict__ bias, float* __restrict__ OUT) {
    int t = threadIdx.x, w = t >> 6, lane = t & 63;
    int quad = lane >> 4, l16 = lane & 15;
    int row0 = blockIdx.x * 32;
    int colbase = w * 64;

    v4f acc[2][4];
#pragma unroll
    for (int i = 0; i < 2; i++)
#pragma unroll
        for (int j = 0; j < 4; j++) acc[i][j] = (v4f){0.f, 0.f, 0.f, 0.f};

    int r0 = row0 + l16;      if (r0 >= N_NODES) r0 = N_NODES - 1;
    int r1 = row0 + 16 + l16; if (r1 >= N_NODES) r1 = N_NODES - 1;
    const half8* a0 = (const half8*)(A + (size_t)r0 * 256 + quad * 8);
    const half8* a1 = (const half8*)(A + (size_t)r1 * 256 + quad * 8);
    const half8* bp[4];
#pragma unroll
    for (int ct = 0; ct < 4; ct++)
        bp[ct] = (const half8*)(Bt + (size_t)(colbase + ct * 16 + l16) * 256 + quad * 8);

#pragma unroll
    for (int kc = 0; kc < 8; kc++) {
        half8 av0 = a0[kc * 4];
        half8 av1 = a1[kc * 4];
#pragma unroll
        for (int ct = 0; ct < 4; ct++) {
            half8 bv = bp[ct][kc * 4];
            acc[0][ct] = __builtin_amdgcn_mfma_f32_16x16x32_f16(av0, bv, acc[0][ct], 0, 0, 0);
            acc[1][ct] = __builtin_amdgcn_mfma_f32_16x16x32_f16(av1, bv, acc[1][ct], 0, 0, 0);
        }
    }

    __shared__ float SF[16][260];
#pragma unroll
    for (int rt = 0; rt < 2; rt++) {
        if (rt) __syncthreads();
#pragma unroll
        for (int ct = 0; ct < 4; ct++)
#pragma unroll
            for (int reg = 0; reg < 4; reg++)
                SF[quad * 4 + reg][colbase + ct * 16 + l16] = acc[rt][ct][reg];
        __syncthreads();
#pragma unroll
        for (int j = 0; j < 4; j++) {
            int c = j * 256 + t;
            int row = c >> 6, c4 = c & 63;
            int gr = row0 + rt * 16 + row;
            if (gr < N_NODES) {
                float4 v = *(const float4*)&SF[row][c4 * 4];
                float4 bb = ((const float4*)bias)[c4];
                float4 o = make_float4(v.x + bb.x, v.y + bb.y, v.z + bb.z, v.w + bb.w);
                *(float4*)(OUT + (size_t)gr * 256 + c4 * 4) = o;
            }
        }
    }
}

// ------------------------------------------------------------------
// Layer-1 aggregation, R11: XCD-sliced (h = blockIdx%8) + 8 nodes/
// wave x 8 lanes/node (lane = 4 ch, half4 gather). Unroll-8 edge
// loop: 8 indices batched (2 int4 loads), then 8 H + 8 es gathers
// in flight -> 2 latency rounds per 8 edges, 8 chains/wave.
// Weights computed inline from head-major es/ed (L2-resident).
// ------------------------------------------------------------------
__global__ __launch_bounds__(256) void k_agg1(
    const _Float16* __restrict__ Hs, const float* __restrict__ esh,
    const float* __restrict__ edh, const int* __restrict__ offsets,
    const int* __restrict__ csr_src, const float* __restrict__ b1,
    const float* __restrict__ vs2, const float* __restrict__ vd2,
    _Float16* __restrict__ out1s, float* __restrict__ es2,
    float* __restrict__ ed2) {
    int t = threadIdx.x, w = t >> 6, lane = t & 63;
    int h  = blockIdx.x & 7;        // slice == XCD (round-robin dispatch)
    int gb = blockIdx.x >> 3;
    int g  = lane >> 3;             // node group 0..7
    int c4 = lane & 7;              // 4-channel quad within 32-ch slice
    int nn = gb * 32 + w * 8 + g;   // 1563*32 = 50016 (tail dupes)
    bool valid = nn < N_NODES;
    int n = valid ? nn : N_NODES - 1;

    int beg = offsets[n];
    int deg = offsets[n + 1] - beg;
    float edn = edh[(size_t)h * N_NODES + n];

    const _Float16* __restrict__ Hb  = Hs + (size_t)h * N_NODES * 32 + c4 * 4;
    const float* __restrict__    esb = esh + (size_t)h * N_NODES;
    const int* __restrict__      sb  = csr_src + beg;

    float a0 = 0.f, a1 = 0.f, a2 = 0.f, a3 = 0.f, den = 0.f;
    for (int base = 0; base < deg; base += 8) {
        int4u sv0 = *(const int4u*)(sb + base);
        int4u sv1 = *(const int4u*)(sb + base + 4);
        int s[8] = {sv0[0], sv0[1], sv0[2], sv0[3],
                    sv1[0], sv1[1], sv1[2], sv1[3]};
        int s0c = s[0];
#pragma unroll
        for (int j = 1; j < 8; j++)
            if (base + j >= deg) s[j] = s0c;   // clamp padded slots
        float ev[8];
        half4 hv[8];
#pragma unroll
        for (int j = 0; j < 8; j++) {
            ev[j] = esb[s[j]];
            hv[j] = *(const half4*)(Hb + (size_t)s[j] * 32);
        }
#pragma unroll
        for (int j = 0; j < 8; j++) {
            float l = ev[j] + edn;
            l = fmaxf(l, 0.2f * l);
            float wt = (base + j < deg) ? __expf(l) : 0.f;
            a0 += wt * (float)hv[j][0]; a1 += wt * (float)hv[j][1];
            a2 += wt * (float)hv[j][2]; a3 += wt * (float)hv[j][3];
            den += wt;
        }
    }

    float r = 1.f / (den + 1e-16f);
    int c = h * 32 + c4 * 4;
    float4 bb = *(const float4*)(b1 + c);
    float o0 = a0 * r + bb.x, o1 = a1 * r + bb.y;
    float o2 = a2 * r + bb.z, o3 = a3 * r + bb.w;
    o0 = o0 > 0.f ? o0 : __expf(o0) - 1.f;   // ELU
    o1 = o1 > 0.f ? o1 : __expf(o1) - 1.f;
    o2 = o2 > 0.f ? o2 : __expf(o2) - 1.f;
    o3 = o3 > 0.f ? o3 : __expf(o3) - 1.f;
    *(half4*)(out1s + ((size_t)h * N_NODES + n) * 32 + c4 * 4) =
        (half4){(_Float16)o0, (_Float16)o1, (_Float16)o2, (_Float16)o3};

    // fused layer-2 attention coefficient partials (this slice's 32 ch)
    float4 vs = *(const float4*)(vs2 + c);
    float4 vd = *(const float4*)(vd2 + c);
    float ps = o0 * vs.x + o1 * vs.y + o2 * vs.z + o3 * vs.w;
    float pd = o0 * vd.x + o1 * vd.y + o2 * vd.z + o3 * vd.w;
#pragma unroll
    for (int mk = 1; mk < 8; mk <<= 1) {
        ps += __shfl_xor(ps, mk, 64);
        pd += __shfl_xor(pd, mk, 64);
    }
    if (c4 == 0 && valid) {
        atomicAdd(&es2[n], ps);
        atomicAdd(&ed2[n], pd);
    }
}

// ------------------------------------------------------------------
// Layer-2 aggregation, R11: same structure, single-head weights
// from es2/ed2 (complete after k_agg1). xagg row-major for GEMM2.
// ------------------------------------------------------------------
__global__ __launch_bounds__(256) void k_agg2(
    const _Float16* __restrict__ O1s, const float* __restrict__ es2,
    const float* __restrict__ ed2, const int* __restrict__ offsets,
    const int* __restrict__ csr_src, _Float16* __restrict__ xagg) {
    int t = threadIdx.x, w = t >> 6, lane = t & 63;
    int h  = blockIdx.x & 7;
    int gb = blockIdx.x >> 3;
    int g  = lane >> 3;
    int c4 = lane & 7;
    int nn = gb * 32 + w * 8 + g;
    bool valid = nn < N_NODES;
    int n = valid ? nn : N_NODES - 1;

    int beg = offsets[n];
    int deg = offsets[n + 1] - beg;
    float edn = ed2[n];

    const _Float16* __restrict__ Ob = O1s + (size_t)h * N_NODES * 32 + c4 * 4;
    const int* __restrict__     sb  = csr_src + beg;

    float a0 = 0.f, a1 = 0.f, a2 = 0.f, a3 = 0.f, den = 0.f;
    for (int base = 0; base < deg; base += 8) {
        int4u sv0 = *(const int4u*)(sb + base);
        int4u sv1 = *(const int4u*)(sb + base + 4);
        int s[8] = {sv0[0], sv0[1], sv0[2], sv0[3],
                    sv1[0], sv1[1], sv1[2], sv1[3]};
        int s0c = s[0];
#pragma unroll
        for (int j = 1; j < 8; j++)
            if (base + j >= deg) s[j] = s0c;
        float ev[8];
        half4 hv[8];
#pragma unroll
        for (int j = 0; j < 8; j++) {
            ev[j] = es2[s[j]];
            hv[j] = *(const half4*)(Ob + (size_t)s[j] * 32);
        }
#pragma unroll
        for (int j = 0; j < 8; j++) {
            float l = ev[j] + edn;
            l = fmaxf(l, 0.2f * l);
            float wt = (base + j < deg) ? __expf(l) : 0.f;
            a0 += wt * (float)hv[j][0]; a1 += wt * (float)hv[j][1];
            a2 += wt * (float)hv[j][2]; a3 += wt * (float)hv[j][3];
            den += wt;
        }
    }

    float r = 1.f / (den + 1e-16f);
    *(half4*)(xagg + (size_t)n * 256 + h * 32 + c4 * 4) =
        (half4){(_Float16)(a0 * r), (_Float16)(a1 * r),
                (_Float16)(a2 * r), (_Float16)(a3 * r)};
}

// ------------------------------------------------------------------
extern "C" void kernel_launch(void* const* d_in, const int* in_sizes, int n_in,
                              void* d_out, int out_size, void* d_ws, size_t ws_size,
                              hipStream_t stream) {
    const float* x   = (const float*)d_in[0];
    const int*   ei  = (const int*)d_in[1];
    const float* W1  = (const float*)d_in[2];
    const float* as1 = (const float*)d_in[3];
    const float* ad1 = (const float*)d_in[4];
    const float* b1  = (const float*)d_in[5];
    const float* W2  = (const float*)d_in[6];
    const float* as2 = (const float*)d_in[7];
    const float* ad2 = (const float*)d_in[8];
    const float* b2  = (const float*)d_in[9];
    float* out = (float*)d_out;

    char* ws = (char*)d_ws;
    size_t off = 0;
    auto alloc = [&](size_t bytes) {
        void* p = ws + off;
        off = (off + bytes + 255) & ~(size_t)255;
        return p;
    };
    _Float16* h1h     = (_Float16*)alloc((size_t)N_NODES * 256 * 2);  // slice-major [8][N][32]
    _Float16* out1h   = (_Float16*)alloc((size_t)N_NODES * 256 * 2);  // slice-major [8][N][32]
    _Float16* xagg    = (_Float16*)alloc((size_t)N_NODES * 256 * 2);  // row-major [N][256]
    _Float16* w1t     = (_Float16*)alloc((size_t)128 * 256 * 2);
    _Float16* w2t     = (_Float16*)alloc((size_t)256 * 256 * 2);
    float*    es1     = (float*)alloc((size_t)N_NODES * 8 * 4);       // head-major [8][N]
    float*    ed1     = (float*)alloc((size_t)N_NODES * 8 * 4);       // head-major [8][N]
    float*    es2     = (float*)alloc((size_t)N_NODES * 4);
    float*    ed2     = (float*)alloc((size_t)N_NODES * 4);
    float*    vs2     = (float*)alloc(256 * 4);
    float*    vd2     = (float*)alloc(256 * 4);
    int*      deg     = (int*)alloc((size_t)N_NODES * 4);
    int*      offsets = (int*)alloc((size_t)(N_NODES + 1) * 4);
    int*      cur     = (int*)alloc((size_t)N_NODES * 4);
    int*      csr_src = (int*)alloc((size_t)E_TOT * 4);
    int*      bsum    = (int*)alloc((size_t)NB * 4);
    int*      boff    = (int*)alloc((size_t)(NB + 1) * 4);

    const int TB = 256;
    int gridE = (E_TOT + TB - 1) / TB;
    int gridG = (N_NODES + 31) / 32;   // 32-row GEMM tiles
    int gridA = AGG_GB * 8;            // 32 nodes/block x 1563 x 8 slices

    // CSR build (deg zeroed by memset; count fused into prepw)
    hipMemsetAsync(deg, 0, (size_t)N_NODES * 4, stream);
    hipMemsetAsync(es2, 0, (size_t)N_NODES * 4, stream);
    hipMemsetAsync(ed2, 0, (size_t)N_NODES * 4, stream);
    int prepN = E_TOT + 128 * 256 + 256 * 256 + 256;
    k_prepw<<<(prepN + TB - 1) / TB, TB, 0, stream>>>(W1, W2, as2, ad2, ei,
                                                      w1t, w2t, vs2, vd2, deg);
    k_blocksum<<<NB, TB, 0, stream>>>(deg, bsum);
    k_scanbsum<<<1, TB, 0, stream>>>(bsum, boff);
    k_offsets<<<NB, TB, 0, stream>>>(deg, boff, offsets, cur);
    k_scatter<<<gridE, TB, 0, stream>>>(ei, cur, csr_src);

    // layer 1
    k_gemm1<<<gridG, TB, 0, stream>>>(x, w1t, as1, ad1, h1h, es1, ed1);
    k_agg1<<<gridA, TB, 0, stream>>>(h1h, es1, ed1, offsets, csr_src, b1,
                                     vs2, vd2, out1h, es2, ed2);

    // layer 2: aggregate first (linearity), then GEMM straight to d_out
    k_agg2<<<gridA, TB, 0, stream>>>(out1h, es2, ed2, offsets, csr_src, xagg);
    k_gemm2<<<gridG, TB, 0, stream>>>(xagg, w2t, b2, out);
}